// Round 1
// baseline (13048.114 us; speedup 1.0000x reference)
//
#include <hip/hip_runtime.h>
#include <math.h>

#define N_NODES 50000
#define P_PATHS 4
#define E_EDGES 800000
#define IN_F 256
#define OUT_F 128

// ---------------- degree counting ----------------
__global__ void deg_kernel(const int* __restrict__ src, const int* __restrict__ dst,
                           float* __restrict__ deg_out, float* __restrict__ deg_in)
{
    int idx = blockIdx.x * blockDim.x + threadIdx.x;
    if (idx >= P_PATHS * E_EDGES) return;
    int p = idx / E_EDGES;
    atomicAdd(&deg_out[p * N_NODES + src[idx]], 1.0f);
    atomicAdd(&deg_in [p * N_NODES + dst[idx]], 1.0f);
}

__global__ void rdeg_kernel(float* __restrict__ buf, int n)
{
    int i = blockIdx.x * blockDim.x + threadIdx.x;
    if (i < n) {
        float v = buf[i];
        buf[i] = rsqrtf(v < 1.0f ? 1.0f : v);
    }
}

// ---------------- xw = (x @ W) * rsqrt(deg_out)  [M=N_NODES, K=256, Nn=128] ----------------
__global__ __launch_bounds__(256) void gemm_xw_kernel(
    const float* __restrict__ A, const float* __restrict__ B,
    const float* __restrict__ srow, float* __restrict__ C,
    int M, int K, int Nn)
{
    __shared__ float As[16][65];   // transposed A tile, padded
    __shared__ float Bs[16][64];
    int m0 = blockIdx.x * 64, n0 = blockIdx.y * 64;
    int t = threadIdx.x;
    int tx = t & 15, ty = t >> 4;
    float acc[4][4] = {};
    for (int k0 = 0; k0 < K; k0 += 16) {
        {   // A tile 64x16 -> As[k][m]
            int row = t >> 2, kk = (t & 3) * 4;
            int gr = m0 + row;
            float4 v = make_float4(0.f, 0.f, 0.f, 0.f);
            if (gr < M) v = *(const float4*)(A + (size_t)gr * K + k0 + kk);
            As[kk + 0][row] = v.x; As[kk + 1][row] = v.y;
            As[kk + 2][row] = v.z; As[kk + 3][row] = v.w;
        }
        {   // B tile 16x64 -> Bs[k][n]
            int kr = t >> 4, cc = (t & 15) * 4;
            float4 v = *(const float4*)(B + (size_t)(k0 + kr) * Nn + n0 + cc);
            Bs[kr][cc + 0] = v.x; Bs[kr][cc + 1] = v.y;
            Bs[kr][cc + 2] = v.z; Bs[kr][cc + 3] = v.w;
        }
        __syncthreads();
#pragma unroll
        for (int k = 0; k < 16; ++k) {
            float a[4], b[4];
#pragma unroll
            for (int i = 0; i < 4; ++i) a[i] = As[k][ty * 4 + i];
#pragma unroll
            for (int j = 0; j < 4; ++j) b[j] = Bs[k][tx * 4 + j];
#pragma unroll
            for (int i = 0; i < 4; ++i)
#pragma unroll
                for (int j = 0; j < 4; ++j) acc[i][j] = fmaf(a[i], b[j], acc[i][j]);
        }
        __syncthreads();
    }
#pragma unroll
    for (int i = 0; i < 4; ++i) {
        int gr = m0 + ty * 4 + i;
        if (gr >= M) continue;
        float s = srow[gr];
        float4 v = make_float4(acc[i][0] * s, acc[i][1] * s, acc[i][2] * s, acc[i][3] * s);
        *(float4*)(C + (size_t)gr * Nn + n0 + tx * 4) = v;
    }
}

// ---------------- agg[dst] += xw[src]  (32 lanes x float4 per edge) ----------------
__global__ void scatter_kernel(const float* __restrict__ xw,
                               const int* __restrict__ src, const int* __restrict__ dst,
                               float* __restrict__ agg)
{
    int idx = blockIdx.x * blockDim.x + threadIdx.x;
    int e = idx >> 5;
    if (e >= E_EDGES) return;
    int j = (idx & 31) * 4;
    int s = src[e], d = dst[e];
    float4 v = *(const float4*)(xw + (size_t)s * OUT_F + j);
    float* o = agg + (size_t)d * OUT_F + j;
    atomicAdd(o + 0, v.x); atomicAdd(o + 1, v.y);
    atomicAdd(o + 2, v.z); atomicAdd(o + 3, v.w);
}

// ---------------- spsum[o] += sum_n tanh( h[n] . fc_w[o] + fc_b[o] ) ----------------
// h[n][k] = agg[n][k]*rdeg_in[n] + bconv[k];  M=N_NODES, K=128, Nn=128
__global__ __launch_bounds__(256) void fc_sp_kernel(
    const float* __restrict__ agg, const float* __restrict__ rdeg_in,
    const float* __restrict__ bconv, const float* __restrict__ fcw,
    const float* __restrict__ fcb, float* __restrict__ spsum, int M)
{
    __shared__ float As[16][65];
    __shared__ float Bs[16][65];
    int m0 = blockIdx.x * 64, n0 = blockIdx.y * 64;
    int t = threadIdx.x;
    int tx = t & 15, ty = t >> 4;
    float acc[4][4] = {};
    for (int k0 = 0; k0 < OUT_F; k0 += 16) {
        {   // A tile: h rows
            int row = t >> 2, kk = (t & 3) * 4;
            int gr = m0 + row;
            float4 v = make_float4(0.f, 0.f, 0.f, 0.f);
            if (gr < M) {
                float s = rdeg_in[gr];
                float4 a  = *(const float4*)(agg + (size_t)gr * OUT_F + k0 + kk);
                float4 bb = *(const float4*)(bconv + k0 + kk);
                v = make_float4(fmaf(a.x, s, bb.x), fmaf(a.y, s, bb.y),
                                fmaf(a.z, s, bb.z), fmaf(a.w, s, bb.w));
            }
            As[kk + 0][row] = v.x; As[kk + 1][row] = v.y;
            As[kk + 2][row] = v.z; As[kk + 3][row] = v.w;
        }
        {   // B tile: Bs[k][o] = fcw[o][k] (transposed load)
            int orow = t >> 2, kk = (t & 3) * 4;
            float4 v = *(const float4*)(fcw + (size_t)(n0 + orow) * OUT_F + k0 + kk);
            Bs[kk + 0][orow] = v.x; Bs[kk + 1][orow] = v.y;
            Bs[kk + 2][orow] = v.z; Bs[kk + 3][orow] = v.w;
        }
        __syncthreads();
#pragma unroll
        for (int k = 0; k < 16; ++k) {
            float a[4], b[4];
#pragma unroll
            for (int i = 0; i < 4; ++i) a[i] = As[k][ty * 4 + i];
#pragma unroll
            for (int j = 0; j < 4; ++j) b[j] = Bs[k][tx * 4 + j];
#pragma unroll
            for (int i = 0; i < 4; ++i)
#pragma unroll
                for (int j = 0; j < 4; ++j) acc[i][j] = fmaf(a[i], b[j], acc[i][j]);
        }
        __syncthreads();
    }
    float colsum[4] = {0.f, 0.f, 0.f, 0.f};
#pragma unroll
    for (int i = 0; i < 4; ++i) {
        int gr = m0 + ty * 4 + i;
        if (gr >= M) continue;
#pragma unroll
        for (int j = 0; j < 4; ++j)
            colsum[j] += tanhf(acc[i][j] + fcb[n0 + tx * 4 + j]);
    }
#pragma unroll
    for (int j = 0; j < 4; ++j) atomicAdd(&spsum[n0 + tx * 4 + j], colsum[j]);
}

// ---------------- beta = softmax_p( att[p] . spsum[p] / N ) ----------------
__global__ void beta_kernel(const float* __restrict__ spsum, const float* __restrict__ att,
                            float* __restrict__ beta)
{
    __shared__ float red[P_PATHS][128];
    int t = threadIdx.x;
    for (int p = 0; p < P_PATHS; ++p)
        red[p][t] = att[p * OUT_F + t] * spsum[p * OUT_F + t] * (1.0f / N_NODES);
    __syncthreads();
    for (int s = 64; s > 0; s >>= 1) {
        if (t < s)
            for (int p = 0; p < P_PATHS; ++p) red[p][t] += red[p][t + s];
        __syncthreads();
    }
    if (t == 0) {
        float w[P_PATHS], mx = -1e30f;
        for (int p = 0; p < P_PATHS; ++p) { w[p] = red[p][0]; mx = fmaxf(mx, w[p]); }
        float sum = 0.f;
        for (int p = 0; p < P_PATHS; ++p) { w[p] = expf(w[p] - mx); sum += w[p]; }
        for (int p = 0; p < P_PATHS; ++p) beta[p] = w[p] / sum;
    }
}

// ---------------- out = sum_p beta[p]*(agg_p*rdeg_in_p + bconv_p) + h_bias ----------------
__global__ void combine_kernel(const float* __restrict__ agg, const float* __restrict__ rdeg_in,
                               const float* __restrict__ bconv, const float* __restrict__ hbias,
                               const float* __restrict__ beta, float* __restrict__ out)
{
    int idx = blockIdx.x * blockDim.x + threadIdx.x;   // over N*OUT/4
    if (idx >= N_NODES * (OUT_F / 4)) return;
    int n = idx >> 5;
    int j = (idx & 31) * 4;
    float4 r = make_float4(0.f, 0.f, 0.f, 0.f);
#pragma unroll
    for (int p = 0; p < P_PATHS; ++p) {
        float bp = beta[p];
        float s = rdeg_in[p * N_NODES + n];
        float4 a  = *(const float4*)(agg + ((size_t)p * N_NODES + n) * OUT_F + j);
        float4 bc = *(const float4*)(bconv + p * OUT_F + j);
        r.x += bp * fmaf(a.x, s, bc.x); r.y += bp * fmaf(a.y, s, bc.y);
        r.z += bp * fmaf(a.z, s, bc.z); r.w += bp * fmaf(a.w, s, bc.w);
    }
    float4 hb = *(const float4*)(hbias + j);
    r.x += hb.x; r.y += hb.y; r.z += hb.z; r.w += hb.w;
    *(float4*)(out + (size_t)idx * 4) = r;
}

extern "C" void kernel_launch(void* const* d_in, const int* in_sizes, int n_in,
                              void* d_out, int out_size, void* d_ws, size_t ws_size,
                              hipStream_t stream)
{
    const float* x      = (const float*)d_in[0];
    const float* W      = (const float*)d_in[1];
    const float* b_conv = (const float*)d_in[2];
    const float* att    = (const float*)d_in[3];
    const float* fc_w   = (const float*)d_in[4];
    const float* fc_b   = (const float*)d_in[5];
    const float* h_bias = (const float*)d_in[6];
    const int*   src    = (const int*)d_in[7];
    const int*   dst    = (const int*)d_in[8];
    float* out = (float*)d_out;
    float* ws  = (float*)d_ws;

    // ws layout (floats)
    size_t off_degout = 0;
    size_t off_degin  = (size_t)P_PATHS * N_NODES;
    size_t off_spsum  = 2 * (size_t)P_PATHS * N_NODES;
    size_t off_beta   = off_spsum + (size_t)P_PATHS * OUT_F;
    size_t off_agg    = (off_beta + P_PATHS + 255) & ~(size_t)255;
    size_t off_xw     = off_agg + (size_t)P_PATHS * N_NODES * OUT_F;

    float* degout = ws + off_degout;
    float* degin  = ws + off_degin;
    float* spsum  = ws + off_spsum;
    float* beta   = ws + off_beta;
    float* agg    = ws + off_agg;
    float* xw     = ws + off_xw;

    // zero accumulators (deg, spsum, beta, agg) every call — harness doesn't re-poison
    hipMemsetAsync(ws, 0, off_xw * sizeof(float), stream);

    deg_kernel<<<(P_PATHS * E_EDGES + 255) / 256, 256, 0, stream>>>(src, dst, degout, degin);
    rdeg_kernel<<<(2 * P_PATHS * N_NODES + 255) / 256, 256, 0, stream>>>(ws, 2 * P_PATHS * N_NODES);

    dim3 ggrid((N_NODES + 63) / 64, OUT_F / 64);
    for (int p = 0; p < P_PATHS; ++p) {
        gemm_xw_kernel<<<ggrid, 256, 0, stream>>>(
            x, W + (size_t)p * IN_F * OUT_F, degout + (size_t)p * N_NODES,
            xw, N_NODES, IN_F, OUT_F);
        scatter_kernel<<<(E_EDGES * 32 + 255) / 256, 256, 0, stream>>>(
            xw, src + (size_t)p * E_EDGES, dst + (size_t)p * E_EDGES,
            agg + (size_t)p * N_NODES * OUT_F);
        fc_sp_kernel<<<ggrid, 256, 0, stream>>>(
            agg + (size_t)p * N_NODES * OUT_F, degin + (size_t)p * N_NODES,
            b_conv + p * OUT_F, fc_w, fc_b, spsum + p * OUT_F, N_NODES);
    }
    beta_kernel<<<1, 128, 0, stream>>>(spsum, att, beta);
    combine_kernel<<<(N_NODES * (OUT_F / 4) + 255) / 256, 256, 0, stream>>>(
        agg, degin, b_conv, h_bias, beta, out);
}

// Round 2
// 1423.152 us; speedup vs baseline: 9.1685x; 9.1685x over previous
//
#include <hip/hip_runtime.h>
#include <math.h>

#define N_NODES 50000
#define P_PATHS 4
#define E_EDGES 800000
#define IN_F 256
#define OUT_F 128
#define NBLK 782   // ceil(N_NODES/64)

// ---------------- degree counting (float counts, exact for ints) ----------------
__global__ void deg_kernel(const int* __restrict__ src, const int* __restrict__ dst,
                           float* __restrict__ deg_out, float* __restrict__ deg_in)
{
    int idx = blockIdx.x * blockDim.x + threadIdx.x;
    if (idx >= P_PATHS * E_EDGES) return;
    int p = idx / E_EDGES;
    atomicAdd(&deg_out[p * N_NODES + src[idx]], 1.0f);
    atomicAdd(&deg_in [p * N_NODES + dst[idx]], 1.0f);
}

// ---------------- per-path exclusive scan of in-degree -> row_start, cursor ----------------
__global__ __launch_bounds__(1024) void scan_kernel(const float* __restrict__ degin,
                                                    int* __restrict__ row_start,
                                                    int* __restrict__ cursor)
{
    int p = blockIdx.x;
    const float* d = degin + (size_t)p * N_NODES;
    int* rs  = row_start + (size_t)p * (N_NODES + 1);
    int* cur = cursor    + (size_t)p * N_NODES;
    __shared__ int bufa[1024], bufb[1024];
    int t = threadIdx.x;
    const int CHUNK = (N_NODES + 1023) / 1024;   // 49
    int lo = t * CHUNK;
    int hi = lo + CHUNK; if (hi > N_NODES) hi = N_NODES; if (lo > N_NODES) lo = N_NODES;
    int s = 0;
    for (int i = lo; i < hi; ++i) s += (int)d[i];
    int* pin = bufa; int* pout = bufb;
    pin[t] = s;
    __syncthreads();
    for (int off = 1; off < 1024; off <<= 1) {
        pout[t] = pin[t] + (t >= off ? pin[t - off] : 0);
        __syncthreads();
        int* tmp = pin; pin = pout; pout = tmp;
    }
    int base = pin[t] - s;   // exclusive prefix
    for (int i = lo; i < hi; ++i) {
        int c = (int)d[i];
        rs[i] = base; cur[i] = base;
        base += c;
    }
    if (t == 1023) rs[N_NODES] = base;   // == E_EDGES
}

__global__ void rdeg_kernel(float* __restrict__ buf, int n)
{
    int i = blockIdx.x * blockDim.x + threadIdx.x;
    if (i < n) {
        float v = buf[i];
        buf[i] = rsqrtf(v < 1.0f ? 1.0f : v);
    }
}

// ---------------- CSR fill: eidx[pos] = src for edges grouped by dst ----------------
__global__ void fill_kernel(const int* __restrict__ src, const int* __restrict__ dst,
                            int* __restrict__ cursor_p, int* __restrict__ eidx)
{
    int e = blockIdx.x * blockDim.x + threadIdx.x;
    if (e >= E_EDGES) return;
    int d = dst[e];
    int pos = atomicAdd(&cursor_p[d], 1);
    eidx[pos] = src[e];
}

// ---------------- xw = (x @ W) * rsqrt(deg_out)  [M=N_NODES, K=256, Nn=128] ----------------
__global__ __launch_bounds__(256) void gemm_xw_kernel(
    const float* __restrict__ A, const float* __restrict__ B,
    const float* __restrict__ srow, float* __restrict__ C,
    int M, int K, int Nn)
{
    __shared__ float As[16][65];
    __shared__ float Bs[16][64];
    int m0 = blockIdx.x * 64, n0 = blockIdx.y * 64;
    int t = threadIdx.x;
    int tx = t & 15, ty = t >> 4;
    float acc[4][4] = {};
    for (int k0 = 0; k0 < K; k0 += 16) {
        {
            int row = t >> 2, kk = (t & 3) * 4;
            int gr = m0 + row;
            float4 v = make_float4(0.f, 0.f, 0.f, 0.f);
            if (gr < M) v = *(const float4*)(A + (size_t)gr * K + k0 + kk);
            As[kk + 0][row] = v.x; As[kk + 1][row] = v.y;
            As[kk + 2][row] = v.z; As[kk + 3][row] = v.w;
        }
        {
            int kr = t >> 4, cc = (t & 15) * 4;
            float4 v = *(const float4*)(B + (size_t)(k0 + kr) * Nn + n0 + cc);
            Bs[kr][cc + 0] = v.x; Bs[kr][cc + 1] = v.y;
            Bs[kr][cc + 2] = v.z; Bs[kr][cc + 3] = v.w;
        }
        __syncthreads();
#pragma unroll
        for (int k = 0; k < 16; ++k) {
            float a[4], b[4];
#pragma unroll
            for (int i = 0; i < 4; ++i) a[i] = As[k][ty * 4 + i];
#pragma unroll
            for (int j = 0; j < 4; ++j) b[j] = Bs[k][tx * 4 + j];
#pragma unroll
            for (int i = 0; i < 4; ++i)
#pragma unroll
                for (int j = 0; j < 4; ++j) acc[i][j] = fmaf(a[i], b[j], acc[i][j]);
        }
        __syncthreads();
    }
#pragma unroll
    for (int i = 0; i < 4; ++i) {
        int gr = m0 + ty * 4 + i;
        if (gr >= M) continue;
        float s = srow[gr];
        float4 v = make_float4(acc[i][0] * s, acc[i][1] * s, acc[i][2] * s, acc[i][3] * s);
        *(float4*)(C + (size_t)gr * Nn + n0 + tx * 4) = v;
    }
}

// ---------------- gather: agg[n][j] = sum_{e in in-edges(n)} xw[src_e][j] ----------------
__global__ __launch_bounds__(128) void gather_kernel(
    const float* __restrict__ xw, const int* __restrict__ eidx,
    const int* __restrict__ row_start, float* __restrict__ aggp)
{
    int n = blockIdx.x;
    int j = threadIdx.x;
    int b = row_start[n], e = row_start[n + 1];
    float acc = 0.f;
    for (int i = b; i < e; ++i) {
        int s = eidx[i];
        acc += xw[(size_t)s * OUT_F + j];
    }
    aggp[(size_t)n * OUT_F + j] = acc;
}

// ---------------- per-block partial column-sums of tanh(h @ fcw^T + fcb) ----------------
// h[n][k] = agg[n][k]*rdeg_in[n] + bconv[k]
__global__ __launch_bounds__(256) void fc_partial_kernel(
    const float* __restrict__ agg, const float* __restrict__ rdeg_in,
    const float* __restrict__ bconv, const float* __restrict__ fcw,
    const float* __restrict__ fcb, float* __restrict__ partial, int M)
{
    __shared__ float As[16][65];
    __shared__ float Bs[16][65];
    __shared__ float red[16][68];
    int m0 = blockIdx.x * 64, n0 = blockIdx.y * 64;
    int t = threadIdx.x;
    int tx = t & 15, ty = t >> 4;
    float acc[4][4] = {};
    for (int k0 = 0; k0 < OUT_F; k0 += 16) {
        {
            int row = t >> 2, kk = (t & 3) * 4;
            int gr = m0 + row;
            float4 v = make_float4(0.f, 0.f, 0.f, 0.f);
            if (gr < M) {
                float s = rdeg_in[gr];
                float4 a  = *(const float4*)(agg + (size_t)gr * OUT_F + k0 + kk);
                float4 bb = *(const float4*)(bconv + k0 + kk);
                v = make_float4(fmaf(a.x, s, bb.x), fmaf(a.y, s, bb.y),
                                fmaf(a.z, s, bb.z), fmaf(a.w, s, bb.w));
            }
            As[kk + 0][row] = v.x; As[kk + 1][row] = v.y;
            As[kk + 2][row] = v.z; As[kk + 3][row] = v.w;
        }
        {
            int orow = t >> 2, kk = (t & 3) * 4;
            float4 v = *(const float4*)(fcw + (size_t)(n0 + orow) * OUT_F + k0 + kk);
            Bs[kk + 0][orow] = v.x; Bs[kk + 1][orow] = v.y;
            Bs[kk + 2][orow] = v.z; Bs[kk + 3][orow] = v.w;
        }
        __syncthreads();
#pragma unroll
        for (int k = 0; k < 16; ++k) {
            float a[4], b[4];
#pragma unroll
            for (int i = 0; i < 4; ++i) a[i] = As[k][ty * 4 + i];
#pragma unroll
            for (int j = 0; j < 4; ++j) b[j] = Bs[k][tx * 4 + j];
#pragma unroll
            for (int i = 0; i < 4; ++i)
#pragma unroll
                for (int j = 0; j < 4; ++j) acc[i][j] = fmaf(a[i], b[j], acc[i][j]);
        }
        __syncthreads();
    }
    float colsum[4] = {0.f, 0.f, 0.f, 0.f};
#pragma unroll
    for (int i = 0; i < 4; ++i) {
        int gr = m0 + ty * 4 + i;
        if (gr >= M) continue;
#pragma unroll
        for (int j = 0; j < 4; ++j)
            colsum[j] += tanhf(acc[i][j] + fcb[n0 + tx * 4 + j]);
    }
#pragma unroll
    for (int j = 0; j < 4; ++j) red[ty][tx * 4 + j] = colsum[j];
    __syncthreads();
    for (int s = 8; s > 0; s >>= 1) {
        if (ty < s) {
#pragma unroll
            for (int j = 0; j < 4; ++j) red[ty][tx * 4 + j] += red[ty + s][tx * 4 + j];
        }
        __syncthreads();
    }
    if (ty == 0) {
#pragma unroll
        for (int j = 0; j < 4; ++j)
            partial[(size_t)blockIdx.x * OUT_F + n0 + tx * 4 + j] = red[0][tx * 4 + j];
    }
}

// ---------------- reduce partials -> sp -> beta softmax ----------------
__global__ __launch_bounds__(512) void beta_reduce_kernel(
    const float* __restrict__ partial, const float* __restrict__ att,
    float* __restrict__ beta)
{
    int t = threadIdx.x;          // 512 = P*128
    int p = t >> 7, c = t & 127;
    float s = 0.f;
    for (int i = 0; i < NBLK; ++i)
        s += partial[((size_t)p * NBLK + i) * OUT_F + c];
    float v = att[p * OUT_F + c] * (s * (1.0f / N_NODES));
    __shared__ float red[512];
    red[t] = v;
    __syncthreads();
    for (int off = 64; off >= 1; off >>= 1) {
        if (c < off) red[t] += red[t + off];
        __syncthreads();
    }
    if (t == 0) {
        float w[P_PATHS], mx = -1e30f;
        for (int q = 0; q < P_PATHS; ++q) { w[q] = red[q * 128]; mx = fmaxf(mx, w[q]); }
        float sum = 0.f;
        for (int q = 0; q < P_PATHS; ++q) { w[q] = expf(w[q] - mx); sum += w[q]; }
        for (int q = 0; q < P_PATHS; ++q) beta[q] = w[q] / sum;
    }
}

// ---------------- out = sum_p beta[p]*(agg_p*rdeg_in_p + bconv_p) + h_bias ----------------
__global__ void combine_kernel(const float* __restrict__ agg, const float* __restrict__ rdeg_in,
                               const float* __restrict__ bconv, const float* __restrict__ hbias,
                               const float* __restrict__ beta, float* __restrict__ out)
{
    int idx = blockIdx.x * blockDim.x + threadIdx.x;
    if (idx >= N_NODES * (OUT_F / 4)) return;
    int n = idx >> 5;
    int j = (idx & 31) * 4;
    float4 r = make_float4(0.f, 0.f, 0.f, 0.f);
#pragma unroll
    for (int p = 0; p < P_PATHS; ++p) {
        float bp = beta[p];
        float s = rdeg_in[p * N_NODES + n];
        float4 a  = *(const float4*)(agg + ((size_t)p * N_NODES + n) * OUT_F + j);
        float4 bc = *(const float4*)(bconv + p * OUT_F + j);
        r.x += bp * fmaf(a.x, s, bc.x); r.y += bp * fmaf(a.y, s, bc.y);
        r.z += bp * fmaf(a.z, s, bc.z); r.w += bp * fmaf(a.w, s, bc.w);
    }
    float4 hb = *(const float4*)(hbias + j);
    r.x += hb.x; r.y += hb.y; r.z += hb.z; r.w += hb.w;
    *(float4*)(out + (size_t)idx * 4) = r;
}

extern "C" void kernel_launch(void* const* d_in, const int* in_sizes, int n_in,
                              void* d_out, int out_size, void* d_ws, size_t ws_size,
                              hipStream_t stream)
{
    const float* x      = (const float*)d_in[0];
    const float* W      = (const float*)d_in[1];
    const float* b_conv = (const float*)d_in[2];
    const float* att    = (const float*)d_in[3];
    const float* fc_w   = (const float*)d_in[4];
    const float* fc_b   = (const float*)d_in[5];
    const float* h_bias = (const float*)d_in[6];
    const int*   src    = (const int*)d_in[7];
    const int*   dst    = (const int*)d_in[8];
    float* out = (float*)d_out;
    float* ws  = (float*)d_ws;

    // ---- ws layout (float units) ----
    size_t off_degout  = 0;                                   // P*N
    size_t off_degin   = off_degout + (size_t)P_PATHS * N_NODES;
    size_t off_partial = off_degin  + (size_t)P_PATHS * N_NODES;      // P*NBLK*128
    size_t off_beta    = off_partial + (size_t)P_PATHS * NBLK * OUT_F;
    size_t off_int     = (off_beta + P_PATHS + 255) & ~(size_t)255;   // int region
    // ints: row_start P*(N+1), cursor P*N, eidx E (shared across paths)
    size_t i_rs   = 0;
    size_t i_cur  = i_rs  + (size_t)P_PATHS * (N_NODES + 1);
    size_t i_eidx = i_cur + (size_t)P_PATHS * N_NODES;
    size_t n_ints = i_eidx + (size_t)E_EDGES;
    size_t off_agg = (off_int + n_ints + 255) & ~(size_t)255;         // P*N*128
    size_t off_xw  = off_agg + (size_t)P_PATHS * N_NODES * OUT_F;     // N*128

    float* degout  = ws + off_degout;
    float* degin   = ws + off_degin;
    float* partial = ws + off_partial;
    float* beta    = ws + off_beta;
    int*   ibase   = (int*)(ws + off_int);
    int*   row_start = ibase + i_rs;
    int*   cursor    = ibase + i_cur;
    int*   eidx      = ibase + i_eidx;
    float* agg     = ws + off_agg;
    float* xw      = ws + off_xw;

    // zero only the degree histograms (everything else fully overwritten)
    hipMemsetAsync(ws, 0, 2 * (size_t)P_PATHS * N_NODES * sizeof(float), stream);

    deg_kernel<<<(P_PATHS * E_EDGES + 255) / 256, 256, 0, stream>>>(src, dst, degout, degin);
    scan_kernel<<<P_PATHS, 1024, 0, stream>>>(degin, row_start, cursor);
    rdeg_kernel<<<(2 * P_PATHS * N_NODES + 255) / 256, 256, 0, stream>>>(ws, 2 * P_PATHS * N_NODES);

    dim3 ggrid(NBLK, OUT_F / 64);
    for (int p = 0; p < P_PATHS; ++p) {
        gemm_xw_kernel<<<ggrid, 256, 0, stream>>>(
            x, W + (size_t)p * IN_F * OUT_F, degout + (size_t)p * N_NODES,
            xw, N_NODES, IN_F, OUT_F);
        fill_kernel<<<(E_EDGES + 255) / 256, 256, 0, stream>>>(
            src + (size_t)p * E_EDGES, dst + (size_t)p * E_EDGES,
            cursor + (size_t)p * N_NODES, eidx);
        gather_kernel<<<N_NODES, 128, 0, stream>>>(
            xw, eidx, row_start + (size_t)p * (N_NODES + 1),
            agg + (size_t)p * N_NODES * OUT_F);
        fc_partial_kernel<<<ggrid, 256, 0, stream>>>(
            agg + (size_t)p * N_NODES * OUT_F, degin + (size_t)p * N_NODES,
            b_conv + p * OUT_F, fc_w, fc_b,
            partial + (size_t)p * NBLK * OUT_F, N_NODES);
    }
    beta_reduce_kernel<<<1, 512, 0, stream>>>(partial, att, beta);
    combine_kernel<<<(N_NODES * (OUT_F / 4) + 255) / 256, 256, 0, stream>>>(
        agg, degin, b_conv, h_bias, beta, out);
}